// Round 4
// baseline (69.292 us; speedup 1.0000x reference)
//
#include <hip/hip_runtime.h>
#include <math.h>

constexpr int NXc = 256, NYc = 256, ETLc = 16, NTc = 100, NBc = 30;
constexpr int NPIX = NXc * NYc;
constexpr int TCHUNK = 25;          // T2 atoms per block (100 = 4 chunks of 25)

// ws layout: [0 .. 256*100)   -> f1 block partials  ws_f1[pixblk*100 + t]   (transposed!)
//            [256*100 .. +256) -> f2 block partials ws_f2[pixblk]

__global__ __launch_bounds__(256) void dm_main(
    const float* __restrict__ sig,      // [NPIX][16]
    const float* __restrict__ db_mag,   // [100][30][16]
    const float* __restrict__ db_b1s,   // [30]
    const float* __restrict__ dtt,      // [16]
    const float* __restrict__ est,      // [2][NPIX]
    float* __restrict__ ws_f1,          // [256][100]
    float* __restrict__ ws_f2)          // [256]
{
    const int tid    = threadIdx.x;
    const int pixblk = blockIdx.x & 255;
    const int tchunk = blockIdx.x >> 8;
    const int p = (pixblk << 8) | tid;
    const int x = p >> 8;
    const int y = p & 255;

    __shared__ float s_part[TCHUNK * 4];
    __shared__ float s_f2[4];

    // --- load & normalize signal (16 floats, 64B aligned) ---
    const float4* sp = reinterpret_cast<const float4*>(sig + (size_t)p * ETLc);
    float s[16];
    {
        float4 a = sp[0], b = sp[1], c = sp[2], d = sp[3];
        s[0]=a.x; s[1]=a.y; s[2]=a.z;  s[3]=a.w;
        s[4]=b.x; s[5]=b.y; s[6]=b.z;  s[7]=b.w;
        s[8]=c.x; s[9]=c.y; s[10]=c.z; s[11]=c.w;
        s[12]=d.x; s[13]=d.y; s[14]=d.z; s[15]=d.w;
    }
    float snrm2 = 0.f;
#pragma unroll
    for (int e = 0; e < 16; ++e) snrm2 = fmaf(s[e], s[e], snrm2);
    const float sig2  = (snrm2 > 0.f) ? 1.0f : 0.0f;
    const float srinv = (snrm2 > 0.f) ? __builtin_amdgcn_rsqf(snrm2) : 0.0f;
    float sgn[16];
#pragma unroll
    for (int e = 0; e < 16; ++e) sgn[e] = s[e] * srinv;

    // --- eta = exp(-dt/t2p) via rcp + exp ---
    const float est0 = est[p];
    const float t2p  = 1.0f + 499.0f * est0;
    const float nrcp = -__builtin_amdgcn_rcpf(t2p);
    float eta[16];
#pragma unroll
    for (int e = 0; e < 16; ++e) eta[e] = __expf(dtt[e] * nrcp);

    // --- nearest b1 grid index (argmin, first occurrence on tie) ---
    const float est1 = est[NPIX + p];
    const float b1   = 0.2f + 1.4f * est1;
    int jb = 0; float best = 3.4e38f;
#pragma unroll
    for (int k = 0; k < NBc; ++k) {
        float d = b1 - db_b1s[k];
        d = d * d;
        if (d < best) { best = d; jb = k; }
    }

    const int wid = tid >> 6, lane = tid & 63;
    const int t0  = tchunk * TCHUNK;
    const float* dbbase = db_mag + ((size_t)t0 * NBc + jb) * ETLc;

    // --- main loop: per-t accumulators live in registers; no cross-lane ops ---
    float acc[TCHUNK];
#pragma unroll
    for (int tt = 0; tt < TCHUNK; ++tt) {
        const float4* dp = reinterpret_cast<const float4*>(dbbase + (size_t)tt * (NBc * ETLc));
        float4 a = dp[0], b = dp[1], c = dp[2], d = dp[3];
        float dbr[16];
        dbr[0]=a.x; dbr[1]=a.y; dbr[2]=a.z;  dbr[3]=a.w;
        dbr[4]=b.x; dbr[5]=b.y; dbr[6]=b.z;  dbr[7]=b.w;
        dbr[8]=c.x; dbr[9]=c.y; dbr[10]=c.z; dbr[11]=c.w;
        dbr[12]=d.x; dbr[13]=d.y; dbr[14]=d.z; dbr[15]=d.w;

        float nrm2 = 0.f, dotv = 0.f;
#pragma unroll
        for (int e = 0; e < 16; ++e) {
            float v = dbr[e] * eta[e];
            nrm2 = fmaf(v, v, nrm2);
            dotv = fmaf(v, sgn[e], dotv);
        }
        float l2sq;
        if (nrm2 > 0.f) l2sq = sig2 + 1.0f - 2.0f * dotv * __builtin_amdgcn_rsqf(nrm2);
        else            l2sq = sig2;
        acc[tt] = (l2sq < 0.f) ? 0.f : l2sq;
    }

    // --- end reduction: 25 independent wave-reduce chains, then cross-wave via LDS ---
#pragma unroll
    for (int tt = 0; tt < TCHUNK; ++tt) {
        float r = acc[tt];
#pragma unroll
        for (int m = 32; m; m >>= 1) r += __shfl_xor(r, m, 64);
        if (lane == 0) s_part[tt * 4 + wid] = r;
    }
    __syncthreads();
    if (tid < TCHUNK) {
        float bsum = s_part[tid*4+0] + s_part[tid*4+1] + s_part[tid*4+2] + s_part[tid*4+3];
        ws_f1[(size_t)pixblk * NTc + (t0 + tid)] = bsum;   // transposed: [pixblk][t]
    }

    // --- f2 (TV of b1) — computed once, by the tchunk==0 blocks ---
    if (tchunk == 0) {
        const float* e1 = est + NPIX;
        float g0, g1;
        {
            float c = b1;
            if (x == 0)            g0 = (0.2f + 1.4f * e1[p + 256]) - c;
            else if (x == NXc - 1) g0 = c - (0.2f + 1.4f * e1[p - 256]);
            else                   g0 = 0.5f * ((0.2f + 1.4f * e1[p + 256]) - (0.2f + 1.4f * e1[p - 256]));
            if (y == 0)            g1 = (0.2f + 1.4f * e1[p + 1]) - c;
            else if (y == NYc - 1) g1 = c - (0.2f + 1.4f * e1[p - 1]);
            else                   g1 = 0.5f * ((0.2f + 1.4f * e1[p + 1]) - (0.2f + 1.4f * e1[p - 1]));
        }
        float r = fabsf(g0) + fabsf(g1);
#pragma unroll
        for (int m = 32; m; m >>= 1) r += __shfl_xor(r, m, 64);
        if (lane == 0) s_f2[wid] = r;
        __syncthreads();
        if (tid == 0) ws_f2[pixblk] = s_f2[0] + s_f2[1] + s_f2[2] + s_f2[3];
    }
}

__global__ __launch_bounds__(128) void dm_final(
    const float* __restrict__ ws_f1,   // [256][100]
    const float* __restrict__ ws_f2,   // [256]
    float* __restrict__ out)
{
    const int tid = threadIdx.x;  // 128 threads
    float v = 0.f;
    if (tid < NTc) {
        // coalesced: lanes 0..99 read consecutive floats per row
        float s0 = 0.f, s1 = 0.f, s2 = 0.f, s3 = 0.f;
        for (int b = 0; b < 256; b += 4) {
            s0 += ws_f1[(size_t)(b    ) * NTc + tid];
            s1 += ws_f1[(size_t)(b + 1) * NTc + tid];
            s2 += ws_f1[(size_t)(b + 2) * NTc + tid];
            s3 += ws_f1[(size_t)(b + 3) * NTc + tid];
        }
        v = sqrtf((s0 + s1) + (s2 + s3));
    }
    v += ws_f2[tid] + ws_f2[tid + 128];

    // reduce 128 threads: wave reduce then combine 2 waves
#pragma unroll
    for (int m = 32; m; m >>= 1) v += __shfl_xor(v, m, 64);
    __shared__ float sred[2];
    if ((tid & 63) == 0) sred[tid >> 6] = v;
    __syncthreads();
    if (tid == 0) out[0] = sred[0] + sred[1];
}

extern "C" void kernel_launch(void* const* d_in, const int* in_sizes, int n_in,
                              void* d_out, int out_size, void* d_ws, size_t ws_size,
                              hipStream_t stream) {
    const float* sig    = (const float*)d_in[0];  // slice_signal (256,256,16)
    const float* db_mag = (const float*)d_in[1];  // (100,30,16)
    // d_in[2] = db_t2s_ms — unused by the reference
    const float* db_b1s = (const float*)d_in[3];  // (30,)
    const float* dtt    = (const float*)d_in[4];  // (16,)
    const float* est    = (const float*)d_in[5];  // (2,256,256)
    float* out = (float*)d_out;

    float* ws_f1 = (float*)d_ws;                  // [256][100]
    float* ws_f2 = ws_f1 + (size_t)256 * NTc;     // [256]

    dm_main<<<dim3(256 * 4), dim3(256), 0, stream>>>(sig, db_mag, db_b1s, dtt, est, ws_f1, ws_f2);
    dm_final<<<dim3(1), dim3(128), 0, stream>>>(ws_f1, ws_f2, out);
}

// Round 5
// 45.922 us; speedup vs baseline: 1.5089x; 1.5089x over previous
//
#include <hip/hip_runtime.h>
#include <math.h>

constexpr int NXc = 256, NYc = 256, ETLc = 16, NTc = 100, NBc = 30;
constexpr int NPIX = NXc * NYc;
constexpr int TCHUNK = 13;          // T2 atoms per block
constexpr int NCHUNK = 8;           // 8*13 = 104 slots, 100 real

// ws layout: [0 .. 256*104)    -> f1 partials ws_f1[pixblk*104 + t]  (t-transposed)
//            [256*104 .. +256) -> f2 partials ws_f2[pixblk]

__global__ __launch_bounds__(256) void dm_main(
    const float* __restrict__ sig,      // [NPIX][16]
    const float* __restrict__ db_mag,   // [100][30][16]
    const float* __restrict__ db_b1s,   // [30]
    const float* __restrict__ dtt,      // [16]
    const float* __restrict__ est,      // [2][NPIX]
    float* __restrict__ ws_f1,          // [256][104]
    float* __restrict__ ws_f2)          // [256]
{
    const int tid    = threadIdx.x;
    const int pixblk = blockIdx.x & 255;
    const int tchunk = blockIdx.x >> 8;   // 0..7
    const int p = (pixblk << 8) | tid;
    const int x = p >> 8;
    const int y = p & 255;

    __shared__ float s_part[TCHUNK * 4];
    __shared__ float s_f2[4];

    // --- load & normalize signal ---
    const float4* sp = reinterpret_cast<const float4*>(sig + (size_t)p * ETLc);
    float s[16];
    {
        float4 a = sp[0], b = sp[1], c = sp[2], d = sp[3];
        s[0]=a.x; s[1]=a.y; s[2]=a.z;  s[3]=a.w;
        s[4]=b.x; s[5]=b.y; s[6]=b.z;  s[7]=b.w;
        s[8]=c.x; s[9]=c.y; s[10]=c.z; s[11]=c.w;
        s[12]=d.x; s[13]=d.y; s[14]=d.z; s[15]=d.w;
    }
    float snrm2 = 0.f;
#pragma unroll
    for (int e = 0; e < 16; ++e) snrm2 = fmaf(s[e], s[e], snrm2);
    const float sig2  = (snrm2 > 0.f) ? 1.0f : 0.0f;
    const float srinv = (snrm2 > 0.f) ? __builtin_amdgcn_rsqf(snrm2) : 0.0f;
    float sgn[16];
#pragma unroll
    for (int e = 0; e < 16; ++e) sgn[e] = s[e] * srinv;

    // --- eta = exp(-dt/t2p) via rcp + fast exp ---
    const float est0 = est[p];
    const float t2p  = 1.0f + 499.0f * est0;
    const float nrcp = -__builtin_amdgcn_rcpf(t2p);
    float eta[16];
#pragma unroll
    for (int e = 0; e < 16; ++e) eta[e] = __expf(dtt[e] * nrcp);

    // --- nearest b1 grid index (argmin, first tie) ---
    const float est1 = est[NPIX + p];
    const float b1   = 0.2f + 1.4f * est1;
    int jb = 0; float best = 3.4e38f;
#pragma unroll
    for (int k = 0; k < NBc; ++k) {
        float d = b1 - db_b1s[k];
        d = d * d;
        if (d < best) { best = d; jb = k; }
    }

    const int wid = tid >> 6, lane = tid & 63;
    const int t0  = tchunk * TCHUNK;
    const float* dbbase = db_mag + ((size_t)t0 * NBc + jb) * ETLc;

    // --- main loop: immediate wave-reduce per t; unroll 2 pairs the chains ---
#pragma unroll 2
    for (int tt = 0; tt < TCHUNK; ++tt) {
        float r = 0.f;
        if (t0 + tt < NTc) {
            const float4* dp = reinterpret_cast<const float4*>(dbbase + (size_t)tt * (NBc * ETLc));
            float4 a = dp[0], b = dp[1], c = dp[2], d = dp[3];
            float dbr[16];
            dbr[0]=a.x; dbr[1]=a.y; dbr[2]=a.z;  dbr[3]=a.w;
            dbr[4]=b.x; dbr[5]=b.y; dbr[6]=b.z;  dbr[7]=b.w;
            dbr[8]=c.x; dbr[9]=c.y; dbr[10]=c.z; dbr[11]=c.w;
            dbr[12]=d.x; dbr[13]=d.y; dbr[14]=d.z; dbr[15]=d.w;

            float nrm2 = 0.f, dotv = 0.f;
#pragma unroll
            for (int e = 0; e < 16; ++e) {
                float v = dbr[e] * eta[e];
                nrm2 = fmaf(v, v, nrm2);
                dotv = fmaf(v, sgn[e], dotv);
            }
            float l2sq;
            if (nrm2 > 0.f) l2sq = sig2 + 1.0f - 2.0f * dotv * __builtin_amdgcn_rsqf(nrm2);
            else            l2sq = sig2;
            r = (l2sq < 0.f) ? 0.f : l2sq;
        }
#pragma unroll
        for (int m = 32; m; m >>= 1) r += __shfl_xor(r, m, 64);
        if (lane == 0) s_part[tt * 4 + wid] = r;
    }
    __syncthreads();
    if (tid < TCHUNK && t0 + tid < NTc) {
        float bsum = s_part[tid*4+0] + s_part[tid*4+1] + s_part[tid*4+2] + s_part[tid*4+3];
        ws_f1[(size_t)pixblk * (TCHUNK * NCHUNK) + (t0 + tid)] = bsum;
    }

    // --- f2 (TV of b1) — once, by tchunk==0 blocks ---
    if (tchunk == 0) {
        const float* e1 = est + NPIX;
        float g0, g1;
        {
            float c = b1;
            if (x == 0)            g0 = (0.2f + 1.4f * e1[p + 256]) - c;
            else if (x == NXc - 1) g0 = c - (0.2f + 1.4f * e1[p - 256]);
            else                   g0 = 0.5f * ((0.2f + 1.4f * e1[p + 256]) - (0.2f + 1.4f * e1[p - 256]));
            if (y == 0)            g1 = (0.2f + 1.4f * e1[p + 1]) - c;
            else if (y == NYc - 1) g1 = c - (0.2f + 1.4f * e1[p - 1]);
            else                   g1 = 0.5f * ((0.2f + 1.4f * e1[p + 1]) - (0.2f + 1.4f * e1[p - 1]));
        }
        float r = fabsf(g0) + fabsf(g1);
#pragma unroll
        for (int m = 32; m; m >>= 1) r += __shfl_xor(r, m, 64);
        if (lane == 0) s_f2[wid] = r;
        __syncthreads();
        if (tid == 0) ws_f2[pixblk] = s_f2[0] + s_f2[1] + s_f2[2] + s_f2[3];
    }
}

__global__ __launch_bounds__(128) void dm_final(
    const float* __restrict__ ws_f1,   // [256][104]
    const float* __restrict__ ws_f2,   // [256]
    float* __restrict__ out)
{
    const int tid = threadIdx.x;  // 128 threads
    constexpr int LD = TCHUNK * NCHUNK; // 104
    float v = 0.f;
    if (tid < NTc) {
        float s0 = 0.f, s1 = 0.f, s2 = 0.f, s3 = 0.f;
        for (int b = 0; b < 256; b += 4) {
            s0 += ws_f1[(size_t)(b    ) * LD + tid];
            s1 += ws_f1[(size_t)(b + 1) * LD + tid];
            s2 += ws_f1[(size_t)(b + 2) * LD + tid];
            s3 += ws_f1[(size_t)(b + 3) * LD + tid];
        }
        v = sqrtf((s0 + s1) + (s2 + s3));
    }
    v += ws_f2[tid] + ws_f2[tid + 128];

#pragma unroll
    for (int m = 32; m; m >>= 1) v += __shfl_xor(v, m, 64);
    __shared__ float sred[2];
    if ((tid & 63) == 0) sred[tid >> 6] = v;
    __syncthreads();
    if (tid == 0) out[0] = sred[0] + sred[1];
}

extern "C" void kernel_launch(void* const* d_in, const int* in_sizes, int n_in,
                              void* d_out, int out_size, void* d_ws, size_t ws_size,
                              hipStream_t stream) {
    const float* sig    = (const float*)d_in[0];  // slice_signal (256,256,16)
    const float* db_mag = (const float*)d_in[1];  // (100,30,16)
    // d_in[2] = db_t2s_ms — unused by the reference
    const float* db_b1s = (const float*)d_in[3];  // (30,)
    const float* dtt    = (const float*)d_in[4];  // (16,)
    const float* est    = (const float*)d_in[5];  // (2,256,256)
    float* out = (float*)d_out;

    float* ws_f1 = (float*)d_ws;                        // [256][104]
    float* ws_f2 = ws_f1 + (size_t)256 * (TCHUNK*NCHUNK); // [256]

    dm_main<<<dim3(256 * NCHUNK), dim3(256), 0, stream>>>(sig, db_mag, db_b1s, dtt, est, ws_f1, ws_f2);
    dm_final<<<dim3(1), dim3(128), 0, stream>>>(ws_f1, ws_f2, out);
}